// Round 21
// baseline (221.349 us; speedup 1.0000x reference)
//
#include <hip/hip_runtime.h>

#define VOCAB 53
#define EDIM  16
#define H     32
#define SEQ   512
#define BATCH 4096
#define LOG2E 1.4426950408889634f
#define XRS   142   // xg row stride in f16: 71 words (odd) -> random-v reads spread all 32 banks
#define HS    72    // h-buffer per-col stride in f16 (2-way write banks, free)
#define RSC   2048.0f      // weight-residual scale (2^11): lo stays f16-normal
#define RSCI  (1.0f/2048.0f)
#define CPB   8     // real batch columns per block (cols 8-15 are clamped ride-alongs)

typedef _Float16 f16x8 __attribute__((ext_vector_type(8)));
typedef float f32x4 __attribute__((ext_vector_type(4)));

__device__ __forceinline__ float exp2_hw(float x) {
    float r; asm("v_exp_f32 %0, %1" : "=v"(r) : "v"(x)); return r;
}
// rcp(1 + 2^xs): sigmoid when xs = -log2e * z (scales pre-folded into tables)
__device__ __forceinline__ float sig_exp2(float xs) {
    return __builtin_amdgcn_rcpf(1.0f + exp2_hw(xs));
}

// permuted row rp = 16*m + 4*s + g  <->  original W row g*32 + (4m+s)
// (mfma chunk m gives lane (q,c) the 4 gates i,f,g,o of unit 4m+q in D[0..3])
__device__ __forceinline__ void decode_row(int rp, int& orig, float& scale) {
    int m = rp >> 4, rem = rp & 15, s = rem >> 2, g = rem & 3;
    orig = g * 32 + 4 * m + s;
    scale = (g == 2) ? (-2.0f * LOG2E) : (-LOG2E);   // g doubled: tanh(g)=2*sig(2g)-1
}

// 512 blocks x 256 threads (4 waves) -> 2 independent blocks per CU: two
// phase-independent recurrence chains per SIMD hide each other's serial
// latency (the R16-family's binding constraint; R9's version of this died on
// a 2.5x fatter DS diet). Each block owns 8 real batch elements (MFMA cols
// 8-15 compute clamped-token ride-alongs, never written). Each wave owns row
// chunks w and w+4, sharing one Bhi b128 read; xg for BOTH chunks comes from
// ONE b128 f16 read via the [v][wave][q][8] layout. Weight residual (Alo,
// x2048 f16) kept: 2 MFMAs per chunk, z = D + Dra/2048; h f16-only; c scaled
// by -2log2e. (Numerics identical to R18: measured absmax 0.0.)
__global__ __launch_bounds__(256)
__attribute__((amdgpu_waves_per_eu(2, 2)))
void lstm_seq_classifier(const int* __restrict__ x,
                         const float* __restrict__ emb,
                         const float* __restrict__ W_ih,
                         const float* __restrict__ W_hh,
                         const float* __restrict__ b_ih,
                         const float* __restrict__ b_hh,
                         const float* __restrict__ W_fc,
                         const float* __restrict__ b_fc,
                         float* __restrict__ out) {
    __shared__ _Float16 xgw[VOCAB * XRS];                   // 15,052 B (f16, packed per wave)
    __shared__ _Float16 whi[128 * 32];                      // 8,192 B
    __shared__ _Float16 wlo[128 * 32];                      // 8,192 B (x2048 residual)
    __shared__ __align__(16) _Float16 hhi_buf[2][16][HS];   // 4,608 B
    __shared__ float red[16 * 33];                          // 2,112 B

    const int tid  = threadIdx.x;
    const int lane = tid & 63;
    const int w    = tid >> 6;      // wave 0..3: owns chunks w and w+4
    const int col  = lane & 15;     // MFMA column
    const int q    = lane >> 4;

    // ---- vocab -> packed, scaled gate-preactivation table (f16) ----
    // slot r = w*32 + q*8 + j holds chunk c=(j<4 ? w : w+4), row 16c+4q+(j&3)
    for (int idx = tid; idx < VOCAB * 128; idx += 256) {
        int v = idx >> 7, r = idx & 127;
        int w_ = r >> 5, q_ = (r >> 3) & 3, j = r & 7;
        int c = (j < 4) ? w_ : (w_ + 4);
        int rp = 16 * c + 4 * q_ + (j & 3);
        int orig; float scale; decode_row(rp, orig, scale);
        float acc = b_ih[orig] + b_hh[orig];
        const float* ev = emb + v * EDIM;
        const float* wr = W_ih + orig * EDIM;
#pragma unroll
        for (int e = 0; e < EDIM; ++e) acc += ev[e] * wr[e];
        xgw[v * XRS + r] = (_Float16)(scale * acc);
    }
    // ---- permuted scaled W_hh as f16 hi + scaled f16 residual ----
    for (int idx = tid; idx < 128 * 32; idx += 256) {
        int rp = idx >> 5, k = idx & 31;
        int orig; float scale; decode_row(rp, orig, scale);
        float wv = scale * W_hh[orig * H + k];
        _Float16 hi = (_Float16)wv;
        whi[idx] = hi;
        wlo[idx] = (_Float16)((wv - (float)hi) * RSC);
    }
    for (int idx = tid; idx < 2 * 16 * HS; idx += 256)
        (&hhi_buf[0][0][0])[idx] = (_Float16)0.f;
    __syncthreads();

    const int c0 = w, c1 = w + 4;   // this wave's two row chunks
    const f16x8 Ahi0 = *reinterpret_cast<const f16x8*>(&whi[(16 * c0 + col) * 32 + 8 * q]);
    const f16x8 Alo0 = *reinterpret_cast<const f16x8*>(&wlo[(16 * c0 + col) * 32 + 8 * q]);
    const f16x8 Ahi1 = *reinterpret_cast<const f16x8*>(&whi[(16 * c1 + col) * 32 + 8 * q]);
    const f16x8 Alo1 = *reinterpret_cast<const f16x8*>(&wlo[(16 * c1 + col) * 32 + 8 * q]);

    // token stream; cols >= CPB ride along on clamped (real, bounded) data
    int elem = blockIdx.x * CPB + col;
    if (elem > BATCH - 1) elem = BATCH - 1;
    const long xb = (long)elem * SEQ;
    const int xgoff = w * 32 + q * 8;         // this lane's 8 packed xg values
    int vc = x[xb + 1];
    f32x4 xg_cur0, xg_cur1;
    {
        f16x8 x0 = *reinterpret_cast<const f16x8*>(&xgw[x[xb] * XRS + xgoff]);
        xg_cur0 = f32x4{(float)x0[0], (float)x0[1], (float)x0[2], (float)x0[3]};
        xg_cur1 = f32x4{(float)x0[4], (float)x0[5], (float)x0[6], (float)x0[7]};
    }

    const int u0 = 4 * w + q;        // unit of chunk c0 (0..15)
    const int u1 = 16 + 4 * w + q;   // unit of chunk c1 (16..31)

    float ccs0 = 0.0f, h0 = 0.0f;    // ccs = -2log2e * c
    float ccs1 = 0.0f, h1 = 0.0f;
    const f32x4 zeroC = {0.f, 0.f, 0.f, 0.f};

    for (int s = 0; s < SEQ; ++s) {
        int vn = x[xb + ((s + 2) & (SEQ - 1))];                      // prefetch s+2
        f16x8 xgh_nxt = *reinterpret_cast<const f16x8*>(
            &xgw[vc * XRS + xgoff]);                                 // one b128, 1 step ahead
        const int rb = s & 1, nb = rb ^ 1;
        f16x8 Bhi = *reinterpret_cast<const f16x8*>(&hhi_buf[rb][col][8 * q]);

        // chunk c0 + chunk c1: 4 independent MFMAs total
        f32x4 D0   = __builtin_amdgcn_mfma_f32_16x16x32_f16(Ahi0, Bhi, xg_cur0, 0, 0, 0);
        f32x4 Dra0 = __builtin_amdgcn_mfma_f32_16x16x32_f16(Alo0, Bhi, zeroC, 0, 0, 0);
        f32x4 D1   = __builtin_amdgcn_mfma_f32_16x16x32_f16(Ahi1, Bhi, xg_cur1, 0, 0, 0);
        f32x4 Dra1 = __builtin_amdgcn_mfma_f32_16x16x32_f16(Alo1, Bhi, zeroC, 0, 0, 0);

        float zi0 = __builtin_fmaf(RSCI, Dra0[0], D0[0]);
        float zf0 = __builtin_fmaf(RSCI, Dra0[1], D0[1]);
        float zg0 = __builtin_fmaf(RSCI, Dra0[2], D0[2]);
        float zo0 = __builtin_fmaf(RSCI, Dra0[3], D0[3]);
        float zi1 = __builtin_fmaf(RSCI, Dra1[0], D1[0]);
        float zf1 = __builtin_fmaf(RSCI, Dra1[1], D1[1]);
        float zg1 = __builtin_fmaf(RSCI, Dra1[2], D1[2]);
        float zo1 = __builtin_fmaf(RSCI, Dra1[3], D1[3]);

        float si0 = sig_exp2(zi0), sf0 = sig_exp2(zf0);
        float ug0 = sig_exp2(zg0), so0 = sig_exp2(zo0);
        float si1 = sig_exp2(zi1), sf1 = sig_exp2(zf1);
        float ug1 = sig_exp2(zg1), so1 = sig_exp2(zo1);

        float t10 = __builtin_fmaf(-4.0f * LOG2E, ug0, 2.0f * LOG2E);  // -2l2e*tanh(g)
        float t11 = __builtin_fmaf(-4.0f * LOG2E, ug1, 2.0f * LOG2E);
        ccs0 = __builtin_fmaf(sf0, ccs0, si0 * t10);
        ccs1 = __builtin_fmaf(sf1, ccs1, si1 * t11);
        float tc0 = __builtin_fmaf(2.0f, sig_exp2(ccs0), -1.0f);       // tanh(c)
        float tc1 = __builtin_fmaf(2.0f, sig_exp2(ccs1), -1.0f);
        h0 = so0 * tc0;
        h1 = so1 * tc1;

        hhi_buf[nb][col][u0] = (_Float16)h0;
        hhi_buf[nb][col][u1] = (_Float16)h1;
        __syncthreads();

        // convert prefetched xg for next step (off critical path)
        xg_cur0 = f32x4{(float)xgh_nxt[0], (float)xgh_nxt[1],
                        (float)xgh_nxt[2], (float)xgh_nxt[3]};
        xg_cur1 = f32x4{(float)xgh_nxt[4], (float)xgh_nxt[5],
                        (float)xgh_nxt[6], (float)xgh_nxt[7]};
        vc = vn;
    }

    // ---- final FC (1 unit) + sigmoid over 32 units, cols 0..7 ----
    red[col * 33 + u0] = h0 * W_fc[u0];
    red[col * 33 + u1] = h1 * W_fc[u1];
    __syncthreads();
    if (w == 0) {
        const float* rr = &red[col * 33];
        float p = 0.f;
#pragma unroll
        for (int u = 0; u < 8; ++u) p += rr[8 * q + u];
        p += __shfl_xor(p, 16);
        p += __shfl_xor(p, 32);
        if (lane < CPB) {
            out[blockIdx.x * CPB + lane] = sig_exp2(-LOG2E * (p + b_fc[0]));
        }
    }
}

extern "C" void kernel_launch(void* const* d_in, const int* in_sizes, int n_in,
                              void* d_out, int out_size, void* d_ws, size_t ws_size,
                              hipStream_t stream) {
    const int*   x    = (const int*)d_in[0];
    const float* emb  = (const float*)d_in[1];
    const float* W_ih = (const float*)d_in[2];
    const float* W_hh = (const float*)d_in[3];
    const float* b_ih = (const float*)d_in[4];
    const float* b_hh = (const float*)d_in[5];
    const float* W_fc = (const float*)d_in[6];
    const float* b_fc = (const float*)d_in[7];
    float* out = (float*)d_out;

    dim3 grid(BATCH / CPB);  // 512 blocks -> 2 independent chains per CU
    dim3 block(256);         // 4 waves, two mfma row-chunks each
    lstm_seq_classifier<<<grid, block, 0, stream>>>(x, emb, W_ih, W_hh,
                                                    b_ih, b_hh, W_fc, b_fc, out);
}

// Round 22
// 146.773 us; speedup vs baseline: 1.5081x; 1.5081x over previous
//
#include <hip/hip_runtime.h>

#define VOCAB 53
#define EDIM  16
#define H     32
#define SEQ   512
#define BATCH 4096
#define LOG2E 1.4426950408889634f
#define XRS   132   // xg row stride in f32 words (%4==0 for b128 alignment)
#define HS    72    // h-buffer per-col stride in f16
#define RSC   2048.0f      // weight-residual scale (2^11): lo stays f16-normal
#define RSCI  (1.0f/2048.0f)

typedef _Float16 f16x8 __attribute__((ext_vector_type(8)));
typedef float f32x4 __attribute__((ext_vector_type(4)));

__device__ __forceinline__ float exp2_hw(float x) {
    float r; asm("v_exp_f32 %0, %1" : "=v"(r) : "v"(x)); return r;
}
// rcp(1 + 2^xs): sigmoid when xs = -log2e * z (scales pre-folded into tables)
__device__ __forceinline__ float sig_exp2(float xs) {
    return __builtin_amdgcn_rcpf(1.0f + exp2_hw(xs));
}

// permuted row rp = 16*m + 4*s + g  <->  original W row g*32 + (4m+s)
// (mfma chunk m gives lane (q,c) the 4 gates i,f,g,o of unit 4m+q in D[0..3])
__device__ __forceinline__ void decode_row(int rp, int& orig, float& scale) {
    int m = rp >> 4, rem = rp & 15, s = rem >> 2, g = rem & 3;
    orig = g * 32 + 4 * m + s;
    scale = (g == 2) ? (-2.0f * LOG2E) : (-LOG2E);   // g doubled: tanh(g)=2*sig(2g)-1
}

// CHAMPION (R16 structure, 147.2 us bench / 161.3 us prof, absmax 0.0).
// 256 blocks x 512 threads (8 waves); each block owns 16 batch elements
// (4096 = 256 CUs x 16 MFMA cols exactly — structure is pinned); each wave
// one 16-row MFMA chunk. h exchanged f16-only via double-buffered padded LDS
// plane (one b128 read + one b16 write per lane-step). WEIGHT residual kept
// (Alo, x2048 f16): 2 independent MFMAs, z = D + Dra/2048 — near-f32 preact
// precision. h-quantization error (~1e-4/step, random, contractive
// recurrence) measured absmax 0.0. c kept scaled by -2log2e.
// Measured-null variants (do not re-add): lgkm-only barrier (R17), f16 xg
// table (R18), waves_per_eu pin (R19), setprio/sched_barrier (R14/R15 regress),
// 8-col multi-block (R9/R20 regress 50%+), global xg (R11/R13 regress).
__global__ __launch_bounds__(512, 1)
void lstm_seq_classifier(const int* __restrict__ x,
                         const float* __restrict__ emb,
                         const float* __restrict__ W_ih,
                         const float* __restrict__ W_hh,
                         const float* __restrict__ b_ih,
                         const float* __restrict__ b_hh,
                         const float* __restrict__ W_fc,
                         const float* __restrict__ b_fc,
                         float* __restrict__ out) {
    __shared__ float xg_perm[VOCAB * XRS];                  // 27,984 B (f32 exact)
    __shared__ _Float16 whi[128 * 32];                      // 8,192 B
    __shared__ _Float16 wlo[128 * 32];                      // 8,192 B (x2048 residual)
    __shared__ __align__(16) _Float16 hhi_buf[2][16][HS];   // 4,608 B
    __shared__ float red[16 * 33];                          // 2,112 B

    const int tid  = threadIdx.x;
    const int lane = tid & 63;
    const int w    = tid >> 6;      // wave index = mfma row-chunk m
    const int col  = lane & 15;     // batch column
    const int q    = lane >> 4;

    // ---- vocab -> permuted, scaled gate-preactivation table (f32 exact) ----
    for (int idx = tid; idx < VOCAB * 128; idx += 512) {
        int v = idx >> 7, rp = idx & 127;
        int orig; float scale; decode_row(rp, orig, scale);
        float acc = b_ih[orig] + b_hh[orig];
        const float* ev = emb + v * EDIM;
        const float* wr = W_ih + orig * EDIM;
#pragma unroll
        for (int e = 0; e < EDIM; ++e) acc += ev[e] * wr[e];
        xg_perm[v * XRS + rp] = scale * acc;
    }
    // ---- permuted scaled W_hh as f16 hi + scaled f16 residual ----
    for (int idx = tid; idx < 128 * 32; idx += 512) {
        int rp = idx >> 5, k = idx & 31;
        int orig; float scale; decode_row(rp, orig, scale);
        float wv = scale * W_hh[orig * H + k];
        _Float16 hi = (_Float16)wv;
        whi[idx] = hi;
        wlo[idx] = (_Float16)((wv - (float)hi) * RSC);
    }
    for (int idx = tid; idx < 2 * 16 * HS; idx += 512)
        (&hhi_buf[0][0][0])[idx] = (_Float16)0.f;
    __syncthreads();

    // A fragments: chunk-row = col, k-slot j = unit 8q+j (identity k-order)
    const f16x8 Ahi = *reinterpret_cast<const f16x8*>(&whi[(16 * w + col) * 32 + 8 * q]);
    const f16x8 Alo = *reinterpret_cast<const f16x8*>(&wlo[(16 * w + col) * 32 + 8 * q]);

    const long xb = (long)(blockIdx.x * 16 + col) * SEQ;
    const int xoff = 16 * w + 4 * q;
    int vc = x[xb + 1];
    f32x4 xg_cur = *reinterpret_cast<const f32x4*>(&xg_perm[x[xb] * XRS + xoff]);

    float ccs = 0.0f, h = 0.0f;   // ccs = -2log2e * c
    const f32x4 zeroC = {0.f, 0.f, 0.f, 0.f};

    for (int s = 0; s < SEQ; ++s) {
        int vn = x[xb + ((s + 2) & (SEQ - 1))];                      // prefetch s+2
        f32x4 xg_nxt = *reinterpret_cast<const f32x4*>(
            &xg_perm[vc * XRS + xoff]);                              // prefetch s+1
        const int rb = s & 1, nb = rb ^ 1;
        f16x8 Bhi = *reinterpret_cast<const f16x8*>(&hhi_buf[rb][col][8 * q]);

        // two INDEPENDENT MFMAs (1-deep chain), then combine
        f32x4 D   = __builtin_amdgcn_mfma_f32_16x16x32_f16(Ahi, Bhi, xg_cur, 0, 0, 0);
        f32x4 Dra = __builtin_amdgcn_mfma_f32_16x16x32_f16(Alo, Bhi, zeroC, 0, 0, 0);

        float zi = __builtin_fmaf(RSCI, Dra[0], D[0]);
        float zf = __builtin_fmaf(RSCI, Dra[1], D[1]);
        float zg = __builtin_fmaf(RSCI, Dra[2], D[2]);
        float zo = __builtin_fmaf(RSCI, Dra[3], D[3]);

        float si = sig_exp2(zi);                         // sigma(i)
        float sf = sig_exp2(zf);                         // sigma(f)
        float ug = sig_exp2(zg);                         // sigma(2g)
        float so = sig_exp2(zo);                         // sigma(o)
        float t1 = __builtin_fmaf(-4.0f * LOG2E, ug, 2.0f * LOG2E);  // -2l2e*tanh(g)
        ccs = __builtin_fmaf(sf, ccs, si * t1);          // scaled cell
        float tc = __builtin_fmaf(2.0f, sig_exp2(ccs), -1.0f);       // tanh(c)
        h = so * tc;

        hhi_buf[nb][col][4 * w + q] = (_Float16)h;
        __syncthreads();
        xg_cur = xg_nxt;
        vc = vn;
    }

    // ---- final FC (1 unit) + sigmoid: cross-wave reduce over the 32 units ----
    red[col * 33 + 4 * w + q] = h * W_fc[4 * w + q];
    __syncthreads();
    if (w == 0) {
        const float* rr = &red[col * 33];
        float p = 0.f;
#pragma unroll
        for (int u = 0; u < 8; ++u) p += rr[8 * q + u];
        p += __shfl_xor(p, 16);
        p += __shfl_xor(p, 32);
        if (lane < 16) {
            out[blockIdx.x * 16 + col] = sig_exp2(-LOG2E * (p + b_fc[0]));
        }
    }
}

extern "C" void kernel_launch(void* const* d_in, const int* in_sizes, int n_in,
                              void* d_out, int out_size, void* d_ws, size_t ws_size,
                              hipStream_t stream) {
    const int*   x    = (const int*)d_in[0];
    const float* emb  = (const float*)d_in[1];
    const float* W_ih = (const float*)d_in[2];
    const float* W_hh = (const float*)d_in[3];
    const float* b_ih = (const float*)d_in[4];
    const float* b_hh = (const float*)d_in[5];
    const float* W_fc = (const float*)d_in[6];
    const float* b_fc = (const float*)d_in[7];
    float* out = (float*)d_out;

    dim3 grid(BATCH / 16);   // 256 blocks: one 16-elem group per block (1/CU)
    dim3 block(512);         // 8 waves, one mfma row-chunk each
    lstm_seq_classifier<<<grid, block, 0, stream>>>(x, emb, W_ih, W_hh,
                                                    b_ih, b_hh, W_fc, b_fc, out);
}